// Round 3
// baseline (141.932 us; speedup 1.0000x reference)
//
#include <hip/hip_runtime.h>
#include <stdint.h>

#define BATCH 32
#define NH    32
#define KVH   8
#define QPK   4
#define DH    128
#define BS    128
#define NEG   (-1e30f)
#define SCALEF 0.08838834764831845f  // 1/sqrt(128)
#define MAXU  512
#define SPLIT 4   // flash-decoding: WGs per (seq, kv-head)

// Partial-attention kernel: grid = BATCH*KVH*SPLIT WGs of 256 threads.
// WG (b,g,s) processes KV blocks i = s, s+SPLIT, ... of sequence b, head g.
// Wave w owns tokens [w*32, w*32+32) of each block; within a wave, lane =
// (token r = lane&31, D-half = lane>>5). K and V are loaded straight to
// registers (16 x float4 each, contiguous 256B per lane) -- no K staging, so
// LDS is ~19KB and 4 WGs/CU co-reside (4 waves/SIMD of TLP hides HBM/L2
// latency; round-2's 1-wave/SIMD hand pipeline couldn't).
// Each WG emits one flash partial (M, S, O[QPK][DH]) to d_ws; a second tiny
// kernel combines the SPLIT partials per (b, head).
__global__ __launch_bounds__(256, 1)
void pa_partial(const float* __restrict__ query,
                const float* __restrict__ key_cache,
                const float* __restrict__ value_cache,
                const float* __restrict__ alibi_blocks,
                const float* __restrict__ alibi_slopes,
                const int* __restrict__ block_list,
                const int* __restrict__ block_groups,
                const int* __restrict__ block_usage,
                float* __restrict__ Mp, float* __restrict__ Sp,
                float* __restrict__ Op,
                int U) {
  __shared__ __align__(16) float q_lds[QPK * DH];     // scaled query
  __shared__ __align__(16) float p_lds[4][32 * QPK];  // per-wave softmax wts
  __shared__ float combO[4][QPK][DH];
  __shared__ float combM[4][QPK];
  __shared__ float combS[4][QPK];
  __shared__ int   ulist[MAXU];
  __shared__ int   pblds[MAXU];
  __shared__ int   uslds[MAXU];
  __shared__ int   ucount;

  const int tid  = threadIdx.x;
  const int w    = tid >> 6;
  const int lane = tid & 63;
  const int r    = lane & 31;
  const int half = lane >> 5;
  const int bid  = blockIdx.x;
  const int b    = bid >> 5;          // / (KVH*SPLIT)
  const int g    = (bid >> 2) & 7;
  const int s    = bid & 3;

  // ---- gather this sequence's block entries (order-preserving) ----
  if (w == 0) {
    int cnt = 0;
    for (int base = 0; base < U; base += 64) {
      const int u = base + lane;
      const bool match = (u < U) && (block_groups[u] == b);
      const unsigned long long mk = __ballot(match);
      if (match) {
        const int pre = __popcll(mk & ((1ull << lane) - 1ull));
        ulist[cnt + pre] = u;
      }
      cnt += __popcll(mk);
    }
    if (lane == 0) ucount = cnt;
    for (int i = lane; i < cnt; i += 64) {
      const int u = ulist[i];
      pblds[i] = block_list[u];
      uslds[i] = block_usage[u];
    }
  }

  // ---- scaled query -> LDS ----
  {
    const float* qsrc = query + ((size_t)b * NH + g * QPK) * DH;
    for (int e = tid; e < QPK * DH; e += 256) q_lds[e] = qsrc[e] * SCALEF;
  }

  float slope[QPK];
#pragma unroll
  for (int qh = 0; qh < QPK; ++qh) slope[qh] = alibi_slopes[g * QPK + qh];

  __syncthreads();

  const int nblk = ucount;

  float m[QPK], sacc[QPK], O[QPK][4];
#pragma unroll
  for (int qh = 0; qh < QPK; ++qh) {
    m[qh] = NEG; sacc[qh] = 0.f;
#pragma unroll
    for (int k = 0; k < 4; ++k) O[qh][k] = 0.f;
  }

  for (int i = s; i < nblk; i += SPLIT) {
    const int u     = ulist[i];
    const int pb    = pblds[i];
    const int usage = uslds[i];

    // ---- K to registers: lane covers token (w*32+r), D-half `half` ----
    const float* kb = key_cache
        + ((size_t)(pb * BS + w * 32 + r) * KVH + g) * DH + half * 64;
    float4 kreg[16];
#pragma unroll
    for (int j = 0; j < 16; ++j) kreg[j] = *(const float4*)&kb[j * 4];

    // ---- V to registers: lane covers d-range r*4, token parity `half` ----
    const float* vb = value_cache
        + ((size_t)(pb * BS + w * 32 + half) * KVH + g) * DH + r * 4;
    float4 vreg[16];
#pragma unroll
    for (int tp = 0; tp < 16; ++tp)
      vreg[tp] = *(const float4*)&vb[(size_t)tp * 2 * (KVH * DH)];

    const float ab = alibi_blocks[(size_t)u * BS + w * 32 + r];

    // ---- QK from registers (q broadcast from LDS) ----
    float acc[QPK] = {0.f, 0.f, 0.f, 0.f};
#pragma unroll
    for (int j = 0; j < 16; ++j) {
      const float4 kv = kreg[j];
#pragma unroll
      for (int qh = 0; qh < QPK; ++qh) {
        const float4 qv = *(const float4*)&q_lds[qh * DH + half * 64 + j * 4];
        acc[qh] += kv.x * qv.x + kv.y * qv.y + kv.z * qv.z + kv.w * qv.w;
      }
    }

    // ---- online softmax over this wave's 32 tokens ----
    const bool valid = (w * 32 + r) < usage;
    float p[QPK];
#pragma unroll
    for (int qh = 0; qh < QPK; ++qh) {
      float sc = acc[qh] + __shfl_xor(acc[qh], 32);
      sc += ab * slope[qh];
      if (!valid) sc = NEG;
      float cm = sc;
#pragma unroll
      for (int off = 1; off < 32; off <<= 1) cm = fmaxf(cm, __shfl_xor(cm, off));
      const float mnew = fmaxf(m[qh], cm);
      const float rs   = __expf(m[qh] - mnew);
      m[qh] = mnew;
      p[qh] = valid ? __expf(sc - mnew) : 0.f;
      sacc[qh] = sacc[qh] * rs + (half == 0 ? p[qh] : 0.f);
#pragma unroll
      for (int k = 0; k < 4; ++k) O[qh][k] *= rs;
    }
    if (half == 0)
      *(float4*)&p_lds[w][r * 4] = make_float4(p[0], p[1], p[2], p[3]);

    // ---- AV from V registers ----
#pragma unroll
    for (int tp = 0; tp < 16; ++tp) {
      const float4 pv = *(const float4*)&p_lds[w][(2 * tp + half) * 4];
      const float4 vv = vreg[tp];
      O[0][0] += pv.x * vv.x; O[0][1] += pv.x * vv.y; O[0][2] += pv.x * vv.z; O[0][3] += pv.x * vv.w;
      O[1][0] += pv.y * vv.x; O[1][1] += pv.y * vv.y; O[1][2] += pv.y * vv.z; O[1][3] += pv.y * vv.w;
      O[2][0] += pv.z * vv.x; O[2][1] += pv.z * vv.y; O[2][2] += pv.z * vv.z; O[2][3] += pv.z * vv.w;
      O[3][0] += pv.w * vv.x; O[3][1] += pv.w * vv.y; O[3][2] += pv.w * vv.z; O[3][3] += pv.w * vv.w;
    }
  }

  // ---- per-wave finalize ----
#pragma unroll
  for (int qh = 0; qh < QPK; ++qh) {
    float sv = sacc[qh];
#pragma unroll
    for (int off = 1; off < 64; off <<= 1) sv += __shfl_xor(sv, off);
#pragma unroll
    for (int k = 0; k < 4; ++k) O[qh][k] += __shfl_xor(O[qh][k], 32);
    if (half == 0) {
#pragma unroll
      for (int k = 0; k < 4; ++k) combO[w][qh][r * 4 + k] = O[qh][k];
    }
    if (lane == 0) { combM[w][qh] = m[qh]; combS[w][qh] = sv; }
  }
  __syncthreads();

  // ---- intra-WG flash combine -> write partial (M, S, O) to workspace ----
  for (int e = tid; e < QPK * DH; e += 256) {
    const int qh = e >> 7;
    const int d  = e & 127;
    float M = combM[0][qh];
#pragma unroll
    for (int ww = 1; ww < 4; ++ww) M = fmaxf(M, combM[ww][qh]);
    float S = 0.f, Ov = 0.f;
#pragma unroll
    for (int ww = 0; ww < 4; ++ww) {
      const float f = __expf(combM[ww][qh] - M);
      S  += f * combS[ww][qh];
      Ov += f * combO[ww][qh][d];
    }
    const int P = ((b * KVH + g) * QPK + qh) * SPLIT + s;
    Op[(size_t)P * DH + d] = Ov;
    if (d == 0) { Mp[P] = M; Sp[P] = S; }
  }
}

// Combine the SPLIT partials per (b, head, d). 524288 threads total.
__global__ __launch_bounds__(256, 1)
void pa_combine(const float* __restrict__ Mp, const float* __restrict__ Sp,
                const float* __restrict__ Op, float* __restrict__ out) {
  const int e  = blockIdx.x * 256 + threadIdx.x;   // == b*4096 + h*128 + d
  const int b  = e >> 12;
  const int h  = (e >> 7) & 31;
  const int d  = e & 127;
  const int g  = h >> 2;
  const int qh = h & 3;
  const int P  = ((b * KVH + g) * QPK + qh) * SPLIT;
  float M = NEG;
#pragma unroll
  for (int s = 0; s < SPLIT; ++s) M = fmaxf(M, Mp[P + s]);
  float S = 0.f, Ov = 0.f;
#pragma unroll
  for (int s = 0; s < SPLIT; ++s) {
    const float f = __expf(Mp[P + s] - M);
    S  += f * Sp[P + s];
    Ov += f * Op[(size_t)(P + s) * DH + d];
  }
  out[e] = Ov / S;
}

extern "C" void kernel_launch(void* const* d_in, const int* in_sizes, int n_in,
                              void* d_out, int out_size, void* d_ws, size_t ws_size,
                              hipStream_t stream) {
  (void)n_in; (void)out_size; (void)ws_size;
  const float* query        = (const float*)d_in[0];
  const float* key_cache    = (const float*)d_in[1];
  const float* value_cache  = (const float*)d_in[2];
  const float* alibi_blocks = (const float*)d_in[3];
  const float* alibi_slopes = (const float*)d_in[4];
  const int*   block_list   = (const int*)d_in[5];
  const int*   block_groups = (const int*)d_in[6];
  const int*   block_usage  = (const int*)d_in[7];
  float*       out          = (float*)d_out;
  const int U = in_sizes[5];

  const int NP = BATCH * KVH * QPK * SPLIT;       // 4096 partials
  float* Mp = (float*)d_ws;
  float* Sp = Mp + NP;
  float* Op = Sp + NP;                            // NP * DH floats

  pa_partial<<<dim3(BATCH * KVH * SPLIT), dim3(256), 0, stream>>>(
      query, key_cache, value_cache, alibi_blocks, alibi_slopes,
      block_list, block_groups, block_usage, Mp, Sp, Op, U);

  pa_combine<<<dim3(BATCH * NH * DH / 256), dim3(256), 0, stream>>>(Mp, Sp, Op, out);
}